// Round 2
// baseline (681.393 us; speedup 1.0000x reference)
//
#include <hip/hip_runtime.h>

#define BN_EPS 1e-5f

__device__ __forceinline__ float elu_f(float x) {
    return x > 0.f ? x : __expf(x) - 1.f;
}

__device__ __forceinline__ unsigned pack_bf2(float a, float b) {
    unsigned ua = __float_as_uint(a), ub = __float_as_uint(b);
    ua = (ua + 0x7fffu + ((ua >> 16) & 1u)) >> 16;
    ub = (ub + 0x7fffu + ((ub >> 16) & 1u)) & 0xffff0000u;
    return ua | ub;
}

// ---------------------------------------------------------------------------
// Tile GEMM: 64 rows x 128 cols per 256-thread block.
// tx = tid&15 -> cols {4tx..4tx+3} and {64+4tx..+3}; ty = tid>>4 -> rows ty+16j.
// A staged in LDS row-major, stride 132 floats.
// ---------------------------------------------------------------------------

__device__ __forceinline__ void gemm_acc(float acc[4][8], float a0, float a1, float a2,
                                         float a3, const float4 wa, const float4 wb) {
    const float w[8] = {wa.x, wa.y, wa.z, wa.w, wb.x, wb.y, wb.z, wb.w};
    const float a[4] = {a0, a1, a2, a3};
#pragma unroll
    for (int j = 0; j < 4; ++j)
#pragma unroll
        for (int u = 0; u < 8; ++u)
            acc[j][u] = fmaf(a[j], w[u], acc[j][u]);
}

__device__ __forceinline__ void gemm_globalW(const float* As, int lda,
                                             const float* __restrict__ Wg, int K,
                                             float acc[4][8], int tx, int ty) {
    const float4* Wg4 = (const float4*)Wg;
#pragma unroll 4
    for (int k = 0; k < K; ++k) {
        float a0 = As[ty * lda + k];
        float a1 = As[(ty + 16) * lda + k];
        float a2 = As[(ty + 32) * lda + k];
        float a3 = As[(ty + 48) * lda + k];
        float4 wa = Wg4[k * 32 + tx];
        float4 wb = Wg4[k * 32 + 16 + tx];
        gemm_acc(acc, a0, a1, a2, a3, wa, wb);
    }
}

// K=128 GEMM with W staged in LDS in 32-row tiles. No trailing barrier --
// caller must __syncthreads() before reusing As/Ws.
__device__ __forceinline__ void gemm_ldsW(const float* As, const float* __restrict__ Wg,
                                          float* Ws, float acc[4][8], int tx, int ty, int tid) {
    for (int k0 = 0; k0 < 128; k0 += 32) {
        __syncthreads();
        const float4* src = (const float4*)(Wg + k0 * 128);
        float4* dst = (float4*)Ws;
#pragma unroll
        for (int i = 0; i < 4; ++i) {
            int f4 = tid + i * 256;
            dst[f4] = src[f4];
        }
        __syncthreads();
#pragma unroll 8
        for (int kk = 0; kk < 32; ++kk) {
            float a0 = As[ty * 132 + k0 + kk];
            float a1 = As[(ty + 16) * 132 + k0 + kk];
            float a2 = As[(ty + 32) * 132 + k0 + kk];
            float a3 = As[(ty + 48) * 132 + k0 + kk];
            float4 wa = *(const float4*)(Ws + kk * 128 + 4 * tx);
            float4 wb = *(const float4*)(Ws + kk * 128 + 64 + 4 * tx);
            gemm_acc(acc, a0, a1, a2, a3, wa, wb);
        }
    }
}

__device__ __forceinline__ void bias_elu(const float acc[4][8], const float* __restrict__ bias,
                                         float vals[4][8], int tx) {
    int ca = 4 * tx, cb = 64 + 4 * tx;
    float bv[8] = {bias[ca], bias[ca + 1], bias[ca + 2], bias[ca + 3],
                   bias[cb], bias[cb + 1], bias[cb + 2], bias[cb + 3]};
#pragma unroll
    for (int j = 0; j < 4; ++j)
#pragma unroll
        for (int u = 0; u < 8; ++u)
            vals[j][u] = elu_f(acc[j][u] + bv[u]);
}

__device__ __forceinline__ void store_tile(float* __restrict__ out, int row0,
                                           const float vals[4][8], int tx, int ty) {
#pragma unroll
    for (int j = 0; j < 4; ++j) {
        int r = row0 + ty + 16 * j;
        *(float4*)(out + r * 128 + 4 * tx) =
            make_float4(vals[j][0], vals[j][1], vals[j][2], vals[j][3]);
        *(float4*)(out + r * 128 + 64 + 4 * tx) =
            make_float4(vals[j][4], vals[j][5], vals[j][6], vals[j][7]);
    }
}

__device__ __forceinline__ void store_tile_bf16(unsigned short* __restrict__ out, int row0,
                                                const float vals[4][8], int tx, int ty) {
#pragma unroll
    for (int j = 0; j < 4; ++j) {
        int r = row0 + ty + 16 * j;
        uint2 pa, pb;
        pa.x = pack_bf2(vals[j][0], vals[j][1]);
        pa.y = pack_bf2(vals[j][2], vals[j][3]);
        pb.x = pack_bf2(vals[j][4], vals[j][5]);
        pb.y = pack_bf2(vals[j][6], vals[j][7]);
        *(uint2*)(out + r * 128 + 4 * tx) = pa;
        *(uint2*)(out + r * 128 + 64 + 4 * tx) = pb;
    }
}

// Column sums + sumsq over the 64-row tile -> atomics into stats. Reuses `red`
// (>= 4096 floats, the As buffer). If aggrow != nullptr, also writes the
// per-column sum there (used by the recv-major mlp2 pass).
__device__ __forceinline__ void stats_tail(const float vals[4][8], float* red,
                                           float* __restrict__ st, float* __restrict__ aggrow,
                                           int tid, int tx, int ty) {
    float ls[8], lq[8];
#pragma unroll
    for (int u = 0; u < 8; ++u) {
        ls[u] = vals[0][u] + vals[1][u] + vals[2][u] + vals[3][u];
        lq[u] = vals[0][u] * vals[0][u] + vals[1][u] * vals[1][u] +
                vals[2][u] * vals[2][u] + vals[3][u] * vals[3][u];
    }
    __syncthreads();  // all As reads done before reuse
    int ca = 4 * tx, cb = 64 + 4 * tx;
#pragma unroll
    for (int u = 0; u < 4; ++u) {
        red[ty * 128 + ca + u] = ls[u];
        red[2048 + ty * 128 + ca + u] = lq[u];
        red[ty * 128 + cb + u] = ls[u + 4];
        red[2048 + ty * 128 + cb + u] = lq[u + 4];
    }
    __syncthreads();
    if (tid < 128) {
        float s = 0.f, q = 0.f;
#pragma unroll
        for (int t = 0; t < 16; ++t) {
            s += red[t * 128 + tid];
            q += red[2048 + t * 128 + tid];
        }
        atomicAdd(st + tid, s);
        atomicAdd(st + 128 + tid, q);
        if (aggrow) aggrow[tid] = s;
    }
}

// ---------------------------------------------------------------------------
// Kernels
// ---------------------------------------------------------------------------

__global__ void k_zero(float* w) {
    int i = blockIdx.x * 256 + threadIdx.x;
    if (i < 2176) w[i] = 0.f;  // 4x512 stats + 128 cvec
}

// stats block layout per stage: [0:128) sum, [128:256) sumsq, [256:384) a, [384:512) shift
__global__ void k_finalize(float* st, float invM, const float* __restrict__ g,
                           const float* __restrict__ beta) {
    int c = threadIdx.x;  // 128
    float mean = st[c] * invM;
    float var = st[128 + c] * invM - mean * mean;
    float a = g[c] * rsqrtf(var + BN_EPS);
    st[256 + c] = a;
    st[384 + c] = beta[c] - mean * a;
}

// mlp1: rows = B*N = 4096, K1 = 40 (transposed gather of inputs), K2 = 128.
__global__ __launch_bounds__(256) void k_mlp1(const float* __restrict__ x,
                                              const float* __restrict__ w1,
                                              const float* __restrict__ b1,
                                              const float* __restrict__ w2,
                                              const float* __restrict__ b2,
                                              float* __restrict__ h1, float* __restrict__ st) {
    __shared__ float Xs[64 * 44];
    __shared__ float As[64 * 132];
    int tid = threadIdx.x, tx = tid & 15, ty = tid >> 4;
    int r0 = blockIdx.x * 64;
    for (int idx = tid; idx < 64 * 40; idx += 256) {
        int r = idx / 40, k = idx - r * 40;
        int rr = r0 + r, b = rr >> 6, n = rr & 63, t = k >> 2, d = k & 3;
        Xs[r * 44 + k] = x[((b * 10 + t) * 64 + n) * 4 + d];
    }
    __syncthreads();
    float acc[4][8] = {};
    gemm_globalW(Xs, 44, w1, 40, acc, tx, ty);
    float vals[4][8];
    bias_elu(acc, b1, vals, tx);
    int ca = 4 * tx, cb = 64 + 4 * tx;
#pragma unroll
    for (int j = 0; j < 4; ++j) {
        int r = ty + 16 * j;
#pragma unroll
        for (int u = 0; u < 4; ++u) {
            As[r * 132 + ca + u] = vals[j][u];
            As[r * 132 + cb + u] = vals[j][u + 4];
        }
    }
    __syncthreads();
    float acc2[4][8] = {};
    gemm_globalW(As, 132, w2, 128, acc2, tx, ty);
    float vals2[4][8];
    bias_elu(acc2, b2, vals2, tx);
    store_tile(h1, r0, vals2, tx, ty);
    stats_tail(vals2, As, st, nullptr, tid, tx, ty);
}

// P/Q precompute: P = BN(h) @ W[0:128], Q = BN(h) @ W[128:256]. 128 blocks.
__global__ __launch_bounds__(256) void k_pq(const float* __restrict__ h,
                                            const float* __restrict__ st,
                                            const float* __restrict__ w,
                                            float* __restrict__ P, float* __restrict__ Q) {
    __shared__ float As[64 * 132];
    int tid = threadIdx.x, tx = tid & 15, ty = tid >> 4;
    int half = blockIdx.x >> 6;
    int r0 = (blockIdx.x & 63) * 64;
    const float* Wg = w + half * 128 * 128;
    float* out = half ? Q : P;
    const float4* h4 = (const float4*)h;
    const float4* av = (const float4*)(st + 256);
    const float4* cv = (const float4*)(st + 384);
#pragma unroll
    for (int i = 0; i < 8; ++i) {
        int f4 = tid + i * 256;
        int r = f4 >> 5, c4 = f4 & 31;
        float4 hv = h4[(r0 + r) * 32 + c4];
        float4 a = av[c4], c = cv[c4];
        float4 v;
        v.x = a.x * hv.x + c.x;
        v.y = a.y * hv.y + c.y;
        v.z = a.z * hv.z + c.z;
        v.w = a.w * hv.w + c.w;
        *(float4*)(As + r * 132 + c4 * 4) = v;
    }
    __syncthreads();
    float acc[4][8] = {};
    gemm_globalW(As, 132, Wg, 128, acc, tx, ty);
#pragma unroll
    for (int j = 0; j < 4; ++j) {
        int r = r0 + ty + 16 * j;
        *(float4*)(out + r * 128 + 4 * tx) = make_float4(acc[j][0], acc[j][1], acc[j][2], acc[j][3]);
        *(float4*)(out + r * 128 + 64 + 4 * tx) = make_float4(acc[j][4], acc[j][5], acc[j][6], acc[j][7]);
    }
}

// Recv-major fused mlp2 + edge2node: one block per (b, recv n). Rows = the 63
// edges with recv n (row 63 = dummy, masked out of stats/agg). Computes
// h2 = elu(elu(P2[s]+Q2[n]+b1) @ w2 + b2) in registers, reduces columns to
// aggraw[b,n,:] (pre-BN sum; no atomics), accumulates BN2 stats.
__global__ __launch_bounds__(256) void k_mlp2agg(const float* __restrict__ P2,
                                                 const float* __restrict__ Q2,
                                                 const float* __restrict__ b1,
                                                 const float* __restrict__ w2,
                                                 const float* __restrict__ b2,
                                                 float* __restrict__ aggraw,
                                                 float* __restrict__ st) {
    __shared__ float As[64 * 132];
    __shared__ float Ws[32 * 128];
    int tid = threadIdx.x, tx = tid & 15, ty = tid >> 4;
    int b = blockIdx.x >> 6, n = blockIdx.x & 63;
    {
        int r = tid & 63, half = tid >> 6;
        int s = (r < 63) ? (r + (r >= n ? 1 : 0)) : n;  // row 63: dummy self-edge
        const float4* Pr = (const float4*)(P2 + (b * 64 + s) * 128);
        const float4* Qr = (const float4*)(Q2 + (b * 64 + n) * 128);
        const float4* B1 = (const float4*)b1;
#pragma unroll
        for (int i = 0; i < 8; ++i) {
            int c4 = half * 8 + i;
            float4 p = Pr[c4], q = Qr[c4], bb = B1[c4];
            float4 v;
            v.x = elu_f(p.x + q.x + bb.x);
            v.y = elu_f(p.y + q.y + bb.y);
            v.z = elu_f(p.z + q.z + bb.z);
            v.w = elu_f(p.w + q.w + bb.w);
            *(float4*)(As + r * 132 + c4 * 4) = v;
        }
    }
    float acc[4][8] = {};
    gemm_ldsW(As, w2, Ws, acc, tx, ty, tid);
    float vals[4][8];
    bias_elu(acc, b2, vals, tx);
    if (ty == 15) {  // row 63 (j==3) is the dummy: exclude from stats & agg
#pragma unroll
        for (int u = 0; u < 8; ++u) vals[3][u] = 0.f;
    }
    stats_tail(vals, As, st, aggraw + (b * 64 + n) * 128, tid, tx, ty);
}

// prep for mlp4 skip path: Wc'[k][c] = a2[k] * W4_1[256+k][c]; cvec[c] += shift2[k]*W..
__global__ void k_wcprep(const float* __restrict__ w41, const float* __restrict__ st2,
                         float* __restrict__ wc, float* __restrict__ cvec) {
    int k = blockIdx.x, c = threadIdx.x;  // 128 x 128
    float w = w41[(256 + k) * 128 + c];
    wc[k * 128 + c] = st2[256 + k] * w;
    atomicAdd(&cvec[c], st2[384 + k] * w);
}

// mlp3: rows = 4096, input = a2*(aggraw/63)+shift2, K=128 both layers.
__global__ __launch_bounds__(256) void k_mlp3(const float* __restrict__ raw,
                                              const float* __restrict__ st2,
                                              const float* __restrict__ w1,
                                              const float* __restrict__ b1,
                                              const float* __restrict__ w2,
                                              const float* __restrict__ b2,
                                              float* __restrict__ h3, float* __restrict__ st) {
    __shared__ float As[64 * 132];
    int tid = threadIdx.x, tx = tid & 15, ty = tid >> 4;
    int r0 = blockIdx.x * 64;
    const float4* in4 = (const float4*)raw;
    const float4* av = (const float4*)(st2 + 256);
    const float4* cv = (const float4*)(st2 + 384);
    const float inv63 = 1.f / 63.f;
#pragma unroll
    for (int i = 0; i < 8; ++i) {
        int f4 = tid + i * 256;
        int r = f4 >> 5, c4 = f4 & 31;
        float4 hv = in4[(r0 + r) * 32 + c4];
        float4 a = av[c4], c = cv[c4];
        float4 v;
        v.x = a.x * hv.x * inv63 + c.x;
        v.y = a.y * hv.y * inv63 + c.y;
        v.z = a.z * hv.z * inv63 + c.z;
        v.w = a.w * hv.w * inv63 + c.w;
        *(float4*)(As + r * 132 + c4 * 4) = v;
    }
    __syncthreads();
    float acc[4][8] = {};
    gemm_globalW(As, 132, w1, 128, acc, tx, ty);
    float vals[4][8];
    bias_elu(acc, b1, vals, tx);
    __syncthreads();
    int ca = 4 * tx, cb = 64 + 4 * tx;
#pragma unroll
    for (int j = 0; j < 4; ++j) {
        int r = ty + 16 * j;
#pragma unroll
        for (int u = 0; u < 4; ++u) {
            As[r * 132 + ca + u] = vals[j][u];
            As[r * 132 + cb + u] = vals[j][u + 4];
        }
    }
    __syncthreads();
    float acc2[4][8] = {};
    gemm_globalW(As, 132, w2, 128, acc2, tx, ty);
    float vals2[4][8];
    bias_elu(acc2, b2, vals2, tx);
    store_tile(h3, r0, vals2, tx, ty);
    stats_tail(vals2, As, st, nullptr, tid, tx, ty);
}

// mlp4 edge kernel (send-major tiles). Recomputes the h2 tile from P2/Q2
// (GEMM1), skip-GEMM with Wc' (GEMM2) + gathered P4/Q4 terms, layer-2 GEMM3,
// stores h4 as bf16 + stats.
__global__ __launch_bounds__(256) void k_mlp4r(const float* __restrict__ P2,
                                               const float* __restrict__ Q2,
                                               const float* __restrict__ m2b1,
                                               const float* __restrict__ m2w2,
                                               const float* __restrict__ m2b2,
                                               const float* __restrict__ P4,
                                               const float* __restrict__ Q4,
                                               const float* __restrict__ wc,
                                               const float* __restrict__ cvec,
                                               const float* __restrict__ b1,
                                               const float* __restrict__ w2,
                                               const float* __restrict__ b2,
                                               unsigned short* __restrict__ h4,
                                               float* __restrict__ st) {
    __shared__ float As[64 * 132];
    __shared__ float Ws[32 * 128];
    int tid = threadIdx.x, tx = tid & 15, ty = tid >> 4;
    unsigned blk = blockIdx.x;
    unsigned b = blk / 63;
    unsigned e0 = (blk - b * 63) * 64;
    int row0 = blk * 64;
    // stage A_skip = elu(P2[s]+Q2[rv]+b1)  (recompute mlp2 layer-1 output)
    {
        int r = tid & 63, half = tid >> 6;
        unsigned e = e0 + r;
        unsigned s = e / 63;
        unsigned j = e - s * 63;
        unsigned rv = j + (j >= s ? 1u : 0u);
        const float4* Pr = (const float4*)(P2 + (b * 64 + s) * 128);
        const float4* Qr = (const float4*)(Q2 + (b * 64 + rv) * 128);
        const float4* B1 = (const float4*)m2b1;
#pragma unroll
        for (int i = 0; i < 8; ++i) {
            int c4 = half * 8 + i;
            float4 p = Pr[c4], q = Qr[c4], bb = B1[c4];
            float4 v;
            v.x = elu_f(p.x + q.x + bb.x);
            v.y = elu_f(p.y + q.y + bb.y);
            v.z = elu_f(p.z + q.z + bb.z);
            v.w = elu_f(p.w + q.w + bb.w);
            *(float4*)(As + r * 132 + c4 * 4) = v;
        }
    }
    // GEMM1: h2 tile
    float acc[4][8] = {};
    gemm_ldsW(As, m2w2, Ws, acc, tx, ty, tid);
    float vals[4][8];
    bias_elu(acc, m2b2, vals, tx);
    __syncthreads();
    int ca = 4 * tx, cb = 64 + 4 * tx;
#pragma unroll
    for (int j = 0; j < 4; ++j) {
        int r = ty + 16 * j;
#pragma unroll
        for (int u = 0; u < 4; ++u) {
            As[r * 132 + ca + u] = vals[j][u];
            As[r * 132 + cb + u] = vals[j][u + 4];
        }
    }
    // GEMM2: skip path h2 @ Wc'
    float acc2[4][8] = {};
    gemm_ldsW(As, wc, Ws, acc2, tx, ty, tid);
    // add gathered node terms + biases, ELU
    {
        const float4* B1 = (const float4*)b1;
        const float4* CV = (const float4*)cvec;
        float4 ba = B1[tx], bb = B1[16 + tx];
        float4 cva = CV[tx], cvb = CV[16 + tx];
#pragma unroll
        for (int j = 0; j < 4; ++j) {
            unsigned e = e0 + ty + 16 * j;
            unsigned s = e / 63;
            unsigned jj = e - s * 63;
            unsigned rv = jj + (jj >= s ? 1u : 0u);
            const float4* Pr = (const float4*)(P4 + (b * 64 + s) * 128);
            const float4* Qr = (const float4*)(Q4 + (b * 64 + rv) * 128);
            float4 pa = Pr[tx], qa = Qr[tx];
            float4 pb = Pr[16 + tx], qb = Qr[16 + tx];
            vals[j][0] = elu_f(acc2[j][0] + pa.x + qa.x + ba.x + cva.x);
            vals[j][1] = elu_f(acc2[j][1] + pa.y + qa.y + ba.y + cva.y);
            vals[j][2] = elu_f(acc2[j][2] + pa.z + qa.z + ba.z + cva.z);
            vals[j][3] = elu_f(acc2[j][3] + pa.w + qa.w + ba.w + cva.w);
            vals[j][4] = elu_f(acc2[j][4] + pb.x + qb.x + bb.x + cvb.x);
            vals[j][5] = elu_f(acc2[j][5] + pb.y + qb.y + bb.y + cvb.y);
            vals[j][6] = elu_f(acc2[j][6] + pb.z + qb.z + bb.z + cvb.z);
            vals[j][7] = elu_f(acc2[j][7] + pb.w + qb.w + bb.w + cvb.w);
        }
    }
    __syncthreads();
#pragma unroll
    for (int j = 0; j < 4; ++j) {
        int r = ty + 16 * j;
#pragma unroll
        for (int u = 0; u < 4; ++u) {
            As[r * 132 + ca + u] = vals[j][u];
            As[r * 132 + cb + u] = vals[j][u + 4];
        }
    }
    // GEMM3: mlp4 layer 2
    float acc3[4][8] = {};
    gemm_ldsW(As, w2, Ws, acc3, tx, ty, tid);
    float vals3[4][8];
    bias_elu(acc3, b2, vals3, tx);
    store_tile_bf16(h4, row0, vals3, tx, ty);
    stats_tail(vals3, As, st, nullptr, tid, tx, ty);
}

// final: out[row,k] = sum_c (a4[c]*h4[row,c]+shift4[c]) * fcw[c,k] + fcb[k]
__global__ __launch_bounds__(256) void k_out(const unsigned short* __restrict__ h4,
                                             const float* __restrict__ st4,
                                             const float* __restrict__ fcw,
                                             const float* __restrict__ fcb,
                                             float* __restrict__ out) {
    int tid = threadIdx.x;
    int lane = tid & 31, rsub = tid >> 5;
    int row = blockIdx.x * 8 + rsub;
    uint2 u = ((const uint2*)(h4 + row * 128))[lane];
    float x0 = __uint_as_float(u.x << 16);
    float x1 = __uint_as_float(u.x & 0xffff0000u);
    float x2 = __uint_as_float(u.y << 16);
    float x3 = __uint_as_float(u.y & 0xffff0000u);
    float4 a = ((const float4*)(st4 + 256))[lane];
    float4 c = ((const float4*)(st4 + 384))[lane];
    x0 = a.x * x0 + c.x;
    x1 = a.y * x1 + c.y;
    x2 = a.z * x2 + c.z;
    x3 = a.w * x3 + c.w;
    const float4* W = (const float4*)(fcw + lane * 8);
    float4 w01 = W[0], w23 = W[1];
    float s0 = x0 * w01.x + x1 * w01.z + x2 * w23.x + x3 * w23.z;
    float s1 = x0 * w01.y + x1 * w01.w + x2 * w23.y + x3 * w23.w;
#pragma unroll
    for (int off = 16; off > 0; off >>= 1) {
        s0 += __shfl_down(s0, off, 32);
        s1 += __shfl_down(s1, off, 32);
    }
    if (lane == 0) {
        out[row * 2] = s0 + fcb[0];
        out[row * 2 + 1] = s1 + fcb[1];
    }
}

// ---------------------------------------------------------------------------

extern "C" void kernel_launch(void* const* d_in, const int* in_sizes, int n_in,
                              void* d_out, int out_size, void* d_ws, size_t ws_size,
                              hipStream_t stream) {
    const float* x = (const float*)d_in[0];
    const float* m1_w1 = (const float*)d_in[1];
    const float* m1_b1 = (const float*)d_in[2];
    const float* m1_w2 = (const float*)d_in[3];
    const float* m1_b2 = (const float*)d_in[4];
    const float* m1_g = (const float*)d_in[5];
    const float* m1_be = (const float*)d_in[6];
    const float* m2_w1 = (const float*)d_in[7];
    const float* m2_b1 = (const float*)d_in[8];
    const float* m2_w2 = (const float*)d_in[9];
    const float* m2_b2 = (const float*)d_in[10];
    const float* m2_g = (const float*)d_in[11];
    const float* m2_be = (const float*)d_in[12];
    const float* m3_w1 = (const float*)d_in[13];
    const float* m3_b1 = (const float*)d_in[14];
    const float* m3_w2 = (const float*)d_in[15];
    const float* m3_b2 = (const float*)d_in[16];
    const float* m3_g = (const float*)d_in[17];
    const float* m3_be = (const float*)d_in[18];
    const float* m4_w1 = (const float*)d_in[19];
    const float* m4_b1 = (const float*)d_in[20];
    const float* m4_w2 = (const float*)d_in[21];
    const float* m4_b2 = (const float*)d_in[22];
    const float* m4_g = (const float*)d_in[23];
    const float* m4_be = (const float*)d_in[24];
    const float* fc_w = (const float*)d_in[25];
    const float* fc_b = (const float*)d_in[26];
    float* out = (float*)d_out;

    // workspace layout. fp32 region: 3,690,496 floats; bf16 h4: 66,060,288 B.
    // total = 80,822,272 B (~81 MB).
    float* W = (float*)d_ws;
    float* stats = W;                 // 4 x 512
    float* cvec = W + 2048;           // 128
    float* h1 = W + 4096;             // 4096x128
    float* P2 = h1 + 524288;
    float* Q2 = P2 + 524288;
    float* aggraw = Q2 + 524288;      // 4096x128 (pre-BN edge2node sums)
    float* h3 = aggraw + 524288;
    float* P4 = h3 + 524288;
    float* Q4 = P4 + 524288;
    float* wc = Q4 + 524288;          // 128x128
    unsigned short* h4b = (unsigned short*)(wc + 16384);  // 258048x128 bf16

    if (ws_size < 80822272u) return;  // safe-fail diagnostic (no OOB fault)

    k_zero<<<9, 256, 0, stream>>>(W);
    k_mlp1<<<64, 256, 0, stream>>>(x, m1_w1, m1_b1, m1_w2, m1_b2, h1, stats);
    k_finalize<<<1, 128, 0, stream>>>(stats, 1.f / 4096.f, m1_g, m1_be);
    k_pq<<<128, 256, 0, stream>>>(h1, stats, m2_w1, P2, Q2);
    k_mlp2agg<<<4096, 256, 0, stream>>>(P2, Q2, m2_b1, m2_w2, m2_b2, aggraw, stats + 512);
    k_finalize<<<1, 128, 0, stream>>>(stats + 512, 1.f / 258048.f, m2_g, m2_be);
    k_wcprep<<<128, 128, 0, stream>>>(m4_w1, stats + 512, wc, cvec);
    k_mlp3<<<64, 256, 0, stream>>>(aggraw, stats + 512, m3_w1, m3_b1, m3_w2, m3_b2, h3,
                                   stats + 1024);
    k_finalize<<<1, 128, 0, stream>>>(stats + 1024, 1.f / 4096.f, m3_g, m3_be);
    k_pq<<<128, 256, 0, stream>>>(h3, stats + 1024, m4_w1, P4, Q4);
    k_mlp4r<<<4032, 256, 0, stream>>>(P2, Q2, m2_b1, m2_w2, m2_b2, P4, Q4, wc, cvec,
                                      m4_b1, m4_w2, m4_b2, h4b, stats + 1536);
    k_finalize<<<1, 128, 0, stream>>>(stats + 1536, 1.f / 258048.f, m4_g, m4_be);
    k_out<<<32256, 256, 0, stream>>>(h4b, stats + 1536, fc_w, fc_b, out);
}

// Round 3
// 449.525 us; speedup vs baseline: 1.5158x; 1.5158x over previous
//
#include <hip/hip_runtime.h>

#define BN_EPS 1e-5f

using h8 = __attribute__((ext_vector_type(8))) _Float16;
using f4v = __attribute__((ext_vector_type(4))) float;

__device__ __forceinline__ float elu_f(float x) {
    return x > 0.f ? x : __expf(x) - 1.f;
}

__device__ __forceinline__ unsigned short bf16r(float x) {
    unsigned u = __float_as_uint(x);
    return (unsigned short)((u + 0x7fffu + ((u >> 16) & 1u)) >> 16);
}

// ---------------------------------------------------------------------------
// fp32 tile GEMM helpers (used by the small node-level kernels only).
// 64 rows x 128 cols per 256-thread block; tx=tid&15 -> cols {4tx..}, {64+4tx..};
// ty=tid>>4 -> rows ty+16j. A in LDS row-major stride 132.
// ---------------------------------------------------------------------------

__device__ __forceinline__ void gemm_acc(float acc[4][8], float a0, float a1, float a2,
                                         float a3, const float4 wa, const float4 wb) {
    const float w[8] = {wa.x, wa.y, wa.z, wa.w, wb.x, wb.y, wb.z, wb.w};
    const float a[4] = {a0, a1, a2, a3};
#pragma unroll
    for (int j = 0; j < 4; ++j)
#pragma unroll
        for (int u = 0; u < 8; ++u)
            acc[j][u] = fmaf(a[j], w[u], acc[j][u]);
}

__device__ __forceinline__ void gemm_globalW(const float* As, int lda,
                                             const float* __restrict__ Wg, int K,
                                             float acc[4][8], int tx, int ty) {
    const float4* Wg4 = (const float4*)Wg;
#pragma unroll 4
    for (int k = 0; k < K; ++k) {
        float a0 = As[ty * lda + k];
        float a1 = As[(ty + 16) * lda + k];
        float a2 = As[(ty + 32) * lda + k];
        float a3 = As[(ty + 48) * lda + k];
        float4 wa = Wg4[k * 32 + tx];
        float4 wb = Wg4[k * 32 + 16 + tx];
        gemm_acc(acc, a0, a1, a2, a3, wa, wb);
    }
}

__device__ __forceinline__ void bias_elu(const float acc[4][8], const float* __restrict__ bias,
                                         float vals[4][8], int tx) {
    int ca = 4 * tx, cb = 64 + 4 * tx;
    float bv[8] = {bias[ca], bias[ca + 1], bias[ca + 2], bias[ca + 3],
                   bias[cb], bias[cb + 1], bias[cb + 2], bias[cb + 3]};
#pragma unroll
    for (int j = 0; j < 4; ++j)
#pragma unroll
        for (int u = 0; u < 8; ++u)
            vals[j][u] = elu_f(acc[j][u] + bv[u]);
}

__device__ __forceinline__ void store_tile(float* __restrict__ out, int row0,
                                           const float vals[4][8], int tx, int ty) {
#pragma unroll
    for (int j = 0; j < 4; ++j) {
        int r = row0 + ty + 16 * j;
        *(float4*)(out + r * 128 + 4 * tx) =
            make_float4(vals[j][0], vals[j][1], vals[j][2], vals[j][3]);
        *(float4*)(out + r * 128 + 64 + 4 * tx) =
            make_float4(vals[j][4], vals[j][5], vals[j][6], vals[j][7]);
    }
}

__device__ __forceinline__ void stats_tail(const float vals[4][8], float* red,
                                           float* __restrict__ st, int tid, int tx, int ty) {
    float ls[8], lq[8];
#pragma unroll
    for (int u = 0; u < 8; ++u) {
        ls[u] = vals[0][u] + vals[1][u] + vals[2][u] + vals[3][u];
        lq[u] = vals[0][u] * vals[0][u] + vals[1][u] * vals[1][u] +
                vals[2][u] * vals[2][u] + vals[3][u] * vals[3][u];
    }
    __syncthreads();
    int ca = 4 * tx, cb = 64 + 4 * tx;
#pragma unroll
    for (int u = 0; u < 4; ++u) {
        red[ty * 128 + ca + u] = ls[u];
        red[2048 + ty * 128 + ca + u] = lq[u];
        red[ty * 128 + cb + u] = ls[u + 4];
        red[2048 + ty * 128 + cb + u] = lq[u + 4];
    }
    __syncthreads();
    if (tid < 128) {
        float s = 0.f, q = 0.f;
#pragma unroll
        for (int t = 0; t < 16; ++t) {
            s += red[t * 128 + tid];
            q += red[2048 + t * 128 + tid];
        }
        atomicAdd(st + tid, s);
        atomicAdd(st + 128 + tid, q);
    }
}

// ---------------------------------------------------------------------------
// MFMA helpers. A-frag LDS layout: Afr[((rt*4+kc)*64 + o*16 + m)*8 + j] =
// act[rt*16+m][kc*32+o*8+j] (fp16). B (weights) prepacked identically:
// Wp[((ct*4+kc)*64 + L)*8 + j] = W[kc*32+(L>>4)*8+j][ct*16+(L&15)].
// One 64x128 tile, K=128: wave w computes rows 0..63 x cols [32w,32w+32).
// ---------------------------------------------------------------------------

__device__ __forceinline__ void mfma_gemm(const _Float16* Afr, const _Float16* Wfr,
                                          f4v acc[4][2], int lane, int w) {
#pragma unroll
    for (int kc = 0; kc < 4; ++kc) {
        h8 af[4];
#pragma unroll
        for (int rt = 0; rt < 4; ++rt)
            af[rt] = *(const h8*)&Afr[((rt * 4 + kc) * 64 + lane) * 8];
#pragma unroll
        for (int ctl = 0; ctl < 2; ++ctl) {
            int ct = w * 2 + ctl;
            h8 bf = *(const h8*)&Wfr[((ct * 4 + kc) * 64 + lane) * 8];
#pragma unroll
            for (int rt = 0; rt < 4; ++rt)
                acc[rt][ctl] = __builtin_amdgcn_mfma_f32_16x16x32_f16(af[rt], bf,
                                                                      acc[rt][ctl], 0, 0, 0);
        }
    }
}

__device__ __forceinline__ void stage_w(_Float16* Wfr, const _Float16* __restrict__ wp,
                                        int tid) {
    const uint4* src = (const uint4*)wp;
    uint4* dst = (uint4*)Wfr;
#pragma unroll
    for (int i = 0; i < 8; ++i) dst[tid + i * 256] = src[tid + i * 256];
}

// write fp32 vals (C-layout) back into A-frag fp16 LDS layout
__device__ __forceinline__ void vals_to_afrag(_Float16* Afr, const float vals[4][2][4],
                                              int lane, int w) {
    int cl = lane & 15, quad = lane >> 4;
#pragma unroll
    for (int ctl = 0; ctl < 2; ++ctl) {
        int col = (w * 2 + ctl) * 16 + cl;
        int kc = col >> 5, o = (col >> 3) & 3, j = col & 7;
#pragma unroll
        for (int rt = 0; rt < 4; ++rt)
#pragma unroll
            for (int i = 0; i < 4; ++i) {
                int m = quad * 4 + i;
                Afr[((rt * 4 + kc) * 64 + o * 16 + m) * 8 + j] = (_Float16)vals[rt][ctl][i];
            }
    }
}

// ---------------------------------------------------------------------------
// Kernels
// ---------------------------------------------------------------------------

__global__ void k_zero(float* w) {
    int i = blockIdx.x * 256 + threadIdx.x;
    if (i < 2176) w[i] = 0.f;  // 4x512 stats + 128 cvec
}

// stats layout per stage: [0:128) sum, [128:256) sumsq, [256:384) a, [384:512) shift
__global__ void k_finalize(float* st, float invM, const float* __restrict__ g,
                           const float* __restrict__ beta) {
    int c = threadIdx.x;
    float mean = st[c] * invM;
    float var = st[128 + c] * invM - mean * mean;
    float a = g[c] * rsqrtf(var + BN_EPS);
    st[256 + c] = a;
    st[384 + c] = beta[c] - mean * a;
}

// pack fp32 W[128][128] (row-major k x col) into MFMA-B fp16 frag layout
__global__ void k_packw(const float* __restrict__ w, _Float16* __restrict__ wp) {
    int flat = blockIdx.x * 256 + threadIdx.x;  // 0..2047
    int g = flat >> 6, L = flat & 63;
    int ct = g >> 2, kc = g & 3;
    int n = ct * 16 + (L & 15), k0 = kc * 32 + (L >> 4) * 8;
    h8 v;
#pragma unroll
    for (int j = 0; j < 8; ++j) v[j] = (_Float16)w[(k0 + j) * 128 + n];
    *(h8*)&wp[flat * 8] = v;
}

// mlp1: rows = B*N = 4096, K1 = 40 (transposed gather of inputs), K2 = 128. fp32.
__global__ __launch_bounds__(256) void k_mlp1(const float* __restrict__ x,
                                              const float* __restrict__ w1,
                                              const float* __restrict__ b1,
                                              const float* __restrict__ w2,
                                              const float* __restrict__ b2,
                                              float* __restrict__ h1, float* __restrict__ st) {
    __shared__ float Xs[64 * 44];
    __shared__ float As[64 * 132];
    int tid = threadIdx.x, tx = tid & 15, ty = tid >> 4;
    int r0 = blockIdx.x * 64;
    for (int idx = tid; idx < 64 * 40; idx += 256) {
        int r = idx / 40, k = idx - r * 40;
        int rr = r0 + r, b = rr >> 6, n = rr & 63, t = k >> 2, d = k & 3;
        Xs[r * 44 + k] = x[((b * 10 + t) * 64 + n) * 4 + d];
    }
    __syncthreads();
    float acc[4][8] = {};
    gemm_globalW(Xs, 44, w1, 40, acc, tx, ty);
    float vals[4][8];
    bias_elu(acc, b1, vals, tx);
    int ca = 4 * tx, cb = 64 + 4 * tx;
#pragma unroll
    for (int j = 0; j < 4; ++j) {
        int r = ty + 16 * j;
#pragma unroll
        for (int u = 0; u < 4; ++u) {
            As[r * 132 + ca + u] = vals[j][u];
            As[r * 132 + cb + u] = vals[j][u + 4];
        }
    }
    __syncthreads();
    float acc2[4][8] = {};
    gemm_globalW(As, 132, w2, 128, acc2, tx, ty);
    float vals2[4][8];
    bias_elu(acc2, b2, vals2, tx);
    store_tile(h1, r0, vals2, tx, ty);
    stats_tail(vals2, As, st, tid, tx, ty);
}

// P/Q precompute: P = BN(h) @ W[0:128], Q = BN(h) @ W[128:256]. fp32, 128 blocks.
__global__ __launch_bounds__(256) void k_pq(const float* __restrict__ h,
                                            const float* __restrict__ st,
                                            const float* __restrict__ w,
                                            float* __restrict__ P, float* __restrict__ Q) {
    __shared__ float As[64 * 132];
    int tid = threadIdx.x, tx = tid & 15, ty = tid >> 4;
    int half = blockIdx.x >> 6;
    int r0 = (blockIdx.x & 63) * 64;
    const float* Wg = w + half * 128 * 128;
    float* out = half ? Q : P;
    const float4* h4 = (const float4*)h;
    const float4* av = (const float4*)(st + 256);
    const float4* cv = (const float4*)(st + 384);
#pragma unroll
    for (int i = 0; i < 8; ++i) {
        int f4 = tid + i * 256;
        int r = f4 >> 5, c4 = f4 & 31;
        float4 hv = h4[(r0 + r) * 32 + c4];
        float4 a = av[c4], c = cv[c4];
        float4 v;
        v.x = a.x * hv.x + c.x;
        v.y = a.y * hv.y + c.y;
        v.z = a.z * hv.z + c.z;
        v.w = a.w * hv.w + c.w;
        *(float4*)(As + r * 132 + c4 * 4) = v;
    }
    __syncthreads();
    float acc[4][8] = {};
    gemm_globalW(As, 132, Wg, 128, acc, tx, ty);
#pragma unroll
    for (int j = 0; j < 4; ++j) {
        int r = r0 + ty + 16 * j;
        *(float4*)(out + r * 128 + 4 * tx) = make_float4(acc[j][0], acc[j][1], acc[j][2], acc[j][3]);
        *(float4*)(out + r * 128 + 64 + 4 * tx) = make_float4(acc[j][4], acc[j][5], acc[j][6], acc[j][7]);
    }
}

// Recv-major fused mlp2 + edge2node (MFMA). One block per (b, recv n); rows =
// 63 real edges + dummy row 63. h2 never stored: column sums -> aggraw, stats.
__global__ __launch_bounds__(256) void k_mlp2agg(const float* __restrict__ P2,
                                                 const float* __restrict__ Q2,
                                                 const float* __restrict__ b1,
                                                 const _Float16* __restrict__ w2p,
                                                 const float* __restrict__ b2,
                                                 float* __restrict__ aggraw,
                                                 float* __restrict__ st) {
    __shared__ _Float16 Afr[8192];   // 16 KB
    __shared__ _Float16 Wfr[16384];  // 32 KB
    int tid = threadIdx.x;
    int lane = tid & 63, w = tid >> 6;
    int b = blockIdx.x >> 6, n = blockIdx.x & 63;
    {  // elementwise: r = lane, kc = w
        int r = lane, kc = w;
        int s = (r < 63) ? (r + (r >= n ? 1 : 0)) : n;
        const float4* Pr = (const float4*)(P2 + (b * 64 + s) * 128);
        const float4* Qr = (const float4*)(Q2 + (b * 64 + n) * 128);
        const float4* B1 = (const float4*)b1;
        int rt = r >> 4, m = r & 15;
#pragma unroll
        for (int o = 0; o < 4; ++o) {
            int c4 = kc * 8 + o * 2;
            float4 p0 = Pr[c4], q0 = Qr[c4], bb0 = B1[c4];
            float4 p1 = Pr[c4 + 1], q1 = Qr[c4 + 1], bb1 = B1[c4 + 1];
            h8 v;
            v[0] = (_Float16)elu_f(p0.x + q0.x + bb0.x);
            v[1] = (_Float16)elu_f(p0.y + q0.y + bb0.y);
            v[2] = (_Float16)elu_f(p0.z + q0.z + bb0.z);
            v[3] = (_Float16)elu_f(p0.w + q0.w + bb0.w);
            v[4] = (_Float16)elu_f(p1.x + q1.x + bb1.x);
            v[5] = (_Float16)elu_f(p1.y + q1.y + bb1.y);
            v[6] = (_Float16)elu_f(p1.z + q1.z + bb1.z);
            v[7] = (_Float16)elu_f(p1.w + q1.w + bb1.w);
            *(h8*)&Afr[((rt * 4 + kc) * 64 + o * 16 + m) * 8] = v;
        }
    }
    stage_w(Wfr, w2p, tid);
    __syncthreads();
    f4v acc[4][2];
#pragma unroll
    for (int rt = 0; rt < 4; ++rt)
#pragma unroll
        for (int c = 0; c < 2; ++c) acc[rt][c] = (f4v){0.f, 0.f, 0.f, 0.f};
    mfma_gemm(Afr, Wfr, acc, lane, w);
    // epilogue: bias+elu, mask dummy row 63, wave-complete column reduce
    int cl = lane & 15, quad = lane >> 4;
#pragma unroll
    for (int ctl = 0; ctl < 2; ++ctl) {
        int col = (w * 2 + ctl) * 16 + cl;
        float bias = b2[col];
        float s1 = 0.f, s2 = 0.f;
#pragma unroll
        for (int rt = 0; rt < 4; ++rt)
#pragma unroll
            for (int i = 0; i < 4; ++i) {
                int row = rt * 16 + quad * 4 + i;
                float v = elu_f(acc[rt][ctl][i] + bias);
                if (row == 63) v = 0.f;
                s1 += v;
                s2 += v * v;
            }
        s1 += __shfl_xor(s1, 16);
        s2 += __shfl_xor(s2, 16);
        s1 += __shfl_xor(s1, 32);
        s2 += __shfl_xor(s2, 32);
        if (quad == 0) {
            aggraw[(b * 64 + n) * 128 + col] = s1;
            atomicAdd(st + col, s1);
            atomicAdd(st + 128 + col, s2);
        }
    }
}

// prep for mlp4 skip path: wcp (fp16, MFMA-B layout) = a2[k]*W4_1[256+k][c];
// cvec[c] += shift2[k]*W4_1[256+k][c]
__global__ void k_wcprep(const float* __restrict__ w41, const float* __restrict__ st2,
                         _Float16* __restrict__ wcp, float* __restrict__ cvec) {
    int k = blockIdx.x, c = threadIdx.x;  // 128 x 128
    float wv = w41[(256 + k) * 128 + c];
    int g = (c >> 4) * 4 + (k >> 5);
    int L = ((k >> 3) & 3) * 16 + (c & 15);
    int j = k & 7;
    wcp[(g * 64 + L) * 8 + j] = (_Float16)(st2[256 + k] * wv);
    atomicAdd(&cvec[c], st2[384 + k] * wv);
}

// mlp3: rows = 4096, input = a2*(aggraw/63)+shift2, K=128 both layers. fp32.
__global__ __launch_bounds__(256) void k_mlp3(const float* __restrict__ raw,
                                              const float* __restrict__ st2,
                                              const float* __restrict__ w1,
                                              const float* __restrict__ b1,
                                              const float* __restrict__ w2,
                                              const float* __restrict__ b2,
                                              float* __restrict__ h3, float* __restrict__ st) {
    __shared__ float As[64 * 132];
    int tid = threadIdx.x, tx = tid & 15, ty = tid >> 4;
    int r0 = blockIdx.x * 64;
    const float4* in4 = (const float4*)raw;
    const float4* av = (const float4*)(st2 + 256);
    const float4* cv = (const float4*)(st2 + 384);
    const float inv63 = 1.f / 63.f;
#pragma unroll
    for (int i = 0; i < 8; ++i) {
        int f4 = tid + i * 256;
        int r = f4 >> 5, c4 = f4 & 31;
        float4 hv = in4[(r0 + r) * 32 + c4];
        float4 a = av[c4], c = cv[c4];
        float4 v;
        v.x = a.x * hv.x * inv63 + c.x;
        v.y = a.y * hv.y * inv63 + c.y;
        v.z = a.z * hv.z * inv63 + c.z;
        v.w = a.w * hv.w * inv63 + c.w;
        *(float4*)(As + r * 132 + c4 * 4) = v;
    }
    __syncthreads();
    float acc[4][8] = {};
    gemm_globalW(As, 132, w1, 128, acc, tx, ty);
    float vals[4][8];
    bias_elu(acc, b1, vals, tx);
    __syncthreads();
    int ca = 4 * tx, cb = 64 + 4 * tx;
#pragma unroll
    for (int j = 0; j < 4; ++j) {
        int r = ty + 16 * j;
#pragma unroll
        for (int u = 0; u < 4; ++u) {
            As[r * 132 + ca + u] = vals[j][u];
            As[r * 132 + cb + u] = vals[j][u + 4];
        }
    }
    __syncthreads();
    float acc2[4][8] = {};
    gemm_globalW(As, 132, w2, 128, acc2, tx, ty);
    float vals2[4][8];
    bias_elu(acc2, b2, vals2, tx);
    store_tile(h3, r0, vals2, tx, ty);
    stats_tail(vals2, As, st, tid, tx, ty);
}

// mlp4 edge kernel (MFMA, send-major tiles). GEMM1 recomputes h2 from P2/Q2,
// GEMM2 = skip path h2 @ Wc', GEMM3 = mlp4 layer 2. Stores h4 bf16 + stats.
__global__ __launch_bounds__(256) void k_mlp4r(const float* __restrict__ P2,
                                               const float* __restrict__ Q2,
                                               const float* __restrict__ m2b1,
                                               const _Float16* __restrict__ w2p2,
                                               const float* __restrict__ m2b2,
                                               const float* __restrict__ P4,
                                               const float* __restrict__ Q4,
                                               const _Float16* __restrict__ wcp,
                                               const float* __restrict__ cvec,
                                               const float* __restrict__ b1,
                                               const _Float16* __restrict__ w4p2,
                                               const float* __restrict__ b2,
                                               unsigned short* __restrict__ h4,
                                               float* __restrict__ st) {
    __shared__ _Float16 Afr[8192];   // 16 KB (also reused as bf16 bounce tile)
    __shared__ _Float16 Wfr[16384];  // 32 KB
    int tid = threadIdx.x;
    int lane = tid & 63, w = tid >> 6;
    unsigned blk = blockIdx.x;
    unsigned b = blk / 63;
    unsigned e0 = (blk - b * 63) * 64;
    int row0 = blk * 64;
    int cl = lane & 15, quad = lane >> 4;
    {  // elementwise A_skip = elu(P2[s]+Q2[rv]+m2b1): r = lane, kc = w
        int r = lane, kc = w;
        unsigned e = e0 + r;
        unsigned s = e / 63;
        unsigned jj = e - s * 63;
        unsigned rv = jj + (jj >= s ? 1u : 0u);
        const float4* Pr = (const float4*)(P2 + (b * 64 + s) * 128);
        const float4* Qr = (const float4*)(Q2 + (b * 64 + rv) * 128);
        const float4* B1 = (const float4*)m2b1;
        int rt = r >> 4, m = r & 15;
#pragma unroll
        for (int o = 0; o < 4; ++o) {
            int c4 = kc * 8 + o * 2;
            float4 p0 = Pr[c4], q0 = Qr[c4], bb0 = B1[c4];
            float4 p1 = Pr[c4 + 1], q1 = Qr[c4 + 1], bb1 = B1[c4 + 1];
            h8 v;
            v[0] = (_Float16)elu_f(p0.x + q0.x + bb0.x);
            v[1] = (_Float16)elu_f(p0.y + q0.y + bb0.y);
            v[2] = (_Float16)elu_f(p0.z + q0.z + bb0.z);
            v[3] = (_Float16)elu_f(p0.w + q0.w + bb0.w);
            v[4] = (_Float16)elu_f(p1.x + q1.x + bb1.x);
            v[5] = (_Float16)elu_f(p1.y + q1.y + bb1.y);
            v[6] = (_Float16)elu_f(p1.z + q1.z + bb1.z);
            v[7] = (_Float16)elu_f(p1.w + q1.w + bb1.w);
            *(h8*)&Afr[((rt * 4 + kc) * 64 + o * 16 + m) * 8] = v;
        }
    }
    stage_w(Wfr, w2p2, tid);
    __syncthreads();
    f4v acc[4][2];
#pragma unroll
    for (int rt = 0; rt < 4; ++rt)
#pragma unroll
        for (int c = 0; c < 2; ++c) acc[rt][c] = (f4v){0.f, 0.f, 0.f, 0.f};
    mfma_gemm(Afr, Wfr, acc, lane, w);
    // epilogue 1: h2 = elu(acc + m2b2[col])
    float vals[4][2][4];
#pragma unroll
    for (int ctl = 0; ctl < 2; ++ctl) {
        float bias = m2b2[(w * 2 + ctl) * 16 + cl];
#pragma unroll
        for (int rt = 0; rt < 4; ++rt)
#pragma unroll
            for (int i = 0; i < 4; ++i)
                vals[rt][ctl][i] = elu_f(acc[rt][ctl][i] + bias);
    }
    __syncthreads();
    vals_to_afrag(Afr, vals, lane, w);
    stage_w(Wfr, wcp, tid);
    __syncthreads();
#pragma unroll
    for (int rt = 0; rt < 4; ++rt)
#pragma unroll
        for (int c = 0; c < 2; ++c) acc[rt][c] = (f4v){0.f, 0.f, 0.f, 0.f};
    mfma_gemm(Afr, Wfr, acc, lane, w);
    // epilogue 2: pre1 = acc + P4[s][col] + Q4[rv][col] + b1[col] + cvec[col] -> elu
#pragma unroll
    for (int ctl = 0; ctl < 2; ++ctl) {
        int col = (w * 2 + ctl) * 16 + cl;
        float base = b1[col] + cvec[col];
#pragma unroll
        for (int rt = 0; rt < 4; ++rt)
#pragma unroll
            for (int i = 0; i < 4; ++i) {
                unsigned e = e0 + rt * 16 + quad * 4 + i;
                unsigned s = e / 63;
                unsigned jj = e - s * 63;
                unsigned rv = jj + (jj >= s ? 1u : 0u);
                float p = P4[(b * 64 + s) * 128 + col];
                float q = Q4[(b * 64 + rv) * 128 + col];
                vals[rt][ctl][i] = elu_f(acc[rt][ctl][i] + p + q + base);
            }
    }
    __syncthreads();
    vals_to_afrag(Afr, vals, lane, w);
    stage_w(Wfr, w4p2, tid);
    __syncthreads();
#pragma unroll
    for (int rt = 0; rt < 4; ++rt)
#pragma unroll
        for (int c = 0; c < 2; ++c) acc[rt][c] = (f4v){0.f, 0.f, 0.f, 0.f};
    mfma_gemm(Afr, Wfr, acc, lane, w);
    // epilogue 3: h4 = elu(acc + b2[col]); stats; bf16 store via LDS bounce
    unsigned short* Tile = (unsigned short*)Afr;
#pragma unroll
    for (int ctl = 0; ctl < 2; ++ctl) {
        int col = (w * 2 + ctl) * 16 + cl;
        float bias = b2[col];
        float s1 = 0.f, s2 = 0.f;
#pragma unroll
        for (int rt = 0; rt < 4; ++rt)
#pragma unroll
            for (int i = 0; i < 4; ++i) {
                float v = elu_f(acc[rt][ctl][i] + bias);
                vals[rt][ctl][i] = v;
                s1 += v;
                s2 += v * v;
            }
        s1 += __shfl_xor(s1, 16);
        s2 += __shfl_xor(s2, 16);
        s1 += __shfl_xor(s1, 32);
        s2 += __shfl_xor(s2, 32);
        if (quad == 0) {
            atomicAdd(st + col, s1);
            atomicAdd(st + 128 + col, s2);
        }
    }
    __syncthreads();  // A-frag reads of GEMM3 complete; reuse Afr as bf16 tile
#pragma unroll
    for (int ctl = 0; ctl < 2; ++ctl) {
        int col = (w * 2 + ctl) * 16 + cl;
#pragma unroll
        for (int rt = 0; rt < 4; ++rt)
#pragma unroll
            for (int i = 0; i < 4; ++i)
                Tile[(rt * 16 + quad * 4 + i) * 128 + col] = bf16r(vals[rt][ctl][i]);
    }
    __syncthreads();
    {  // coalesced bf16 store: thread -> row tid>>2, 32-col quarter tid&3
        int r = tid >> 2, cq = tid & 3;
#pragma unroll
        for (int i = 0; i < 4; ++i) {
            int off = r * 128 + cq * 32 + i * 8;
            *(uint4*)(h4 + (size_t)row0 * 128 + off) = *(uint4*)&Tile[off];
        }
    }
}

// final: out[row,k] = sum_c (a4[c]*h4[row,c]+shift4[c]) * fcw[c,k] + fcb[k]
__global__ __launch_bounds__(256) void k_out(const unsigned short* __restrict__ h4,
                                             const float* __restrict__ st4,
                                             const float* __restrict__ fcw,
                                             const float* __restrict__ fcb,
                                             float* __restrict__ out) {
    int tid = threadIdx.x;
    int lane = tid & 31, rsub = tid >> 5;
    int row = blockIdx.x * 8 + rsub;
    uint2 u = ((const uint2*)(h4 + (size_t)row * 128))[lane];
    float x0 = __uint_as_float(u.x << 16);
    float x1 = __uint_as_float(u.x & 0xffff0000u);
    float x2 = __uint_as_float(u.y << 16);
    float x3 = __uint_as_float(u.y & 0xffff0000u);
    float4 a = ((const float4*)(st4 + 256))[lane];
    float4 c = ((const float4*)(st4 + 384))[lane];
    x0 = a.x * x0 + c.x;
    x1 = a.y * x1 + c.y;
    x2 = a.z * x2 + c.z;
    x3 = a.w * x3 + c.w;
    const float4* W = (const float4*)(fcw + lane * 8);
    float4 w01 = W[0], w23 = W[1];
    float s0 = x0 * w01.x + x1 * w01.z + x2 * w23.x + x3 * w23.z;
    float s1 = x0 * w01.y + x1 * w01.w + x2 * w23.y + x3 * w23.w;
#pragma unroll
    for (int off = 16; off > 0; off >>= 1) {
        s0 += __shfl_down(s0, off, 32);
        s1 += __shfl_down(s1, off, 32);
    }
    if (lane == 0) {
        out[row * 2] = s0 + fcb[0];
        out[row * 2 + 1] = s1 + fcb[1];
    }
}

// ---------------------------------------------------------------------------

extern "C" void kernel_launch(void* const* d_in, const int* in_sizes, int n_in,
                              void* d_out, int out_size, void* d_ws, size_t ws_size,
                              hipStream_t stream) {
    const float* x = (const float*)d_in[0];
    const float* m1_w1 = (const float*)d_in[1];
    const float* m1_b1 = (const float*)d_in[2];
    const float* m1_w2 = (const float*)d_in[3];
    const float* m1_b2 = (const float*)d_in[4];
    const float* m1_g = (const float*)d_in[5];
    const float* m1_be = (const float*)d_in[6];
    const float* m2_w1 = (const float*)d_in[7];
    const float* m2_b1 = (const float*)d_in[8];
    const float* m2_w2 = (const float*)d_in[9];
    const float* m2_b2 = (const float*)d_in[10];
    const float* m2_g = (const float*)d_in[11];
    const float* m2_be = (const float*)d_in[12];
    const float* m3_w1 = (const float*)d_in[13];
    const float* m3_b1 = (const float*)d_in[14];
    const float* m3_w2 = (const float*)d_in[15];
    const float* m3_b2 = (const float*)d_in[16];
    const float* m3_g = (const float*)d_in[17];
    const float* m3_be = (const float*)d_in[18];
    const float* m4_w1 = (const float*)d_in[19];
    const float* m4_b1 = (const float*)d_in[20];
    const float* m4_w2 = (const float*)d_in[21];
    const float* m4_b2 = (const float*)d_in[22];
    const float* m4_g = (const float*)d_in[23];
    const float* m4_be = (const float*)d_in[24];
    const float* fc_w = (const float*)d_in[25];
    const float* fc_b = (const float*)d_in[26];
    float* out = (float*)d_out;

    // workspace layout (float offsets); aggraw aliases h1 (dead after k_pq).
    // total bytes = 3174400*4 + 258048*128*2 = 78,757,888.
    float* W = (float*)d_ws;
    float* stats = W;                   // 4 x 512
    float* cvec = W + 2048;             // 128
    float* h1 = W + 4096;               // 4096x128 (aliased by aggraw)
    float* aggraw = h1;
    float* P2 = W + 528384;
    float* Q2 = W + 1052672;
    float* h3 = W + 1576960;
    float* P4 = W + 2101248;
    float* Q4 = W + 2625536;
    _Float16* w2p2 = (_Float16*)(W + 3149824);  // 16384 fp16
    _Float16* w4p2 = (_Float16*)(W + 3158016);
    _Float16* wcp = (_Float16*)(W + 3166208);
    unsigned short* h4b = (unsigned short*)(W + 3174400);  // 258048x128 bf16

    if (ws_size < 78757888ull) return;  // safe-fail diagnostic (no OOB fault)

    k_zero<<<9, 256, 0, stream>>>(W);
    k_packw<<<8, 256, 0, stream>>>(m2_w2, w2p2);
    k_packw<<<8, 256, 0, stream>>>(m4_w2, w4p2);
    k_mlp1<<<64, 256, 0, stream>>>(x, m1_w1, m1_b1, m1_w2, m1_b2, h1, stats);
    k_finalize<<<1, 128, 0, stream>>>(stats, 1.f / 4096.f, m1_g, m1_be);
    k_pq<<<128, 256, 0, stream>>>(h1, stats, m2_w1, P2, Q2);
    k_mlp2agg<<<4096, 256, 0, stream>>>(P2, Q2, m2_b1, w2p2, m2_b2, aggraw, stats + 512);
    k_finalize<<<1, 128, 0, stream>>>(stats + 512, 1.f / 258048.f, m2_g, m2_be);
    k_wcprep<<<128, 128, 0, stream>>>(m4_w1, stats + 512, wcp, cvec);
    k_mlp3<<<64, 256, 0, stream>>>(aggraw, stats + 512, m3_w1, m3_b1, m3_w2, m3_b2, h3,
                                   stats + 1024);
    k_finalize<<<1, 128, 0, stream>>>(stats + 1024, 1.f / 4096.f, m3_g, m3_be);
    k_pq<<<128, 256, 0, stream>>>(h3, stats + 1024, m4_w1, P4, Q4);
    k_mlp4r<<<4032, 256, 0, stream>>>(P2, Q2, m2_b1, w2p2, m2_b2, P4, Q4, wcp, cvec,
                                      m4_b1, w4p2, m4_b2, h4b, stats + 1536);
    k_finalize<<<1, 128, 0, stream>>>(stats + 1536, 1.f / 258048.f, m4_g, m4_be);
    k_out<<<32256, 256, 0, stream>>>(h4b, stats + 1536, fc_w, fc_b, out);
}